// Round 21
// baseline (440.442 us; speedup 1.0000x reference)
//
#include <hip/hip_runtime.h>
#include <hip/hip_bf16.h>
#include <math.h>

#define D_MODEL 256
#define D_STATE 16
#define D_INNER 512
#define DT_RANK 16
#define NB 4
#define NVAR 32
#define SEG 96
#define TOKENS (NB*NVAR*SEG)   /* 12288 */

typedef float f4 __attribute__((ext_vector_type(4)));

__device__ __forceinline__ float silu_f(float x) { return x / (1.0f + __expf(-x)); }

// ---------------------------------------------------------------------------
// Batched transpose: z in {0,1} picks (W0->WT0) or (W1->WT1).  W: [N][K].
// grid (K/32, N/32, 2), block 256.
// ---------------------------------------------------------------------------
__global__ __launch_bounds__(256)
void transpose_w2(const float* __restrict__ W0, float* __restrict__ WT0,
                  const float* __restrict__ W1, float* __restrict__ WT1,
                  int N, int K)
{
    const float* W  = blockIdx.z ? W1  : W0;
    float*       WT = blockIdx.z ? WT1 : WT0;
    __shared__ float t[32][33];
    const int k0 = blockIdx.x * 32, n0 = blockIdx.y * 32;
    const int tx = threadIdx.x & 31, ty = threadIdx.x >> 5;
#pragma unroll
    for (int i = 0; i < 32; i += 8)
        t[ty + i][tx] = W[(size_t)(n0 + ty + i) * K + k0 + tx];
    __syncthreads();
#pragma unroll
    for (int i = 0; i < 32; i += 8)
        WT[(size_t)(k0 + ty + i) * N + n0 + tx] = t[tx][ty + i];
}

// ---------------------------------------------------------------------------
// NT GEMM v6 (round-15 proven config): C[m,n] = sum_k A[m,k]*WT[k][n].
// 256 thr = 4 waves; BM=32 (wave owns 8 rows; A wave-uniform -> s_load).
// W: coalesced global_load_lds DMA into linear LDS [BK][BN], double-buffered,
// one barrier per K-tile.  Plateau ~53% of fp32 peak -- verified optimal over
// BK{8,16,32}, BN{128,256}, BM{32,64}, A-path{s_load,VMEM,LDS}, pipelining.
// MODE 0 plain; 2: rows (b,v,s)->(b,s,v); 3: inverse.
// ---------------------------------------------------------------------------
template<int K, int BN, int BK, int MODE>
__global__ __launch_bounds__(256, 4)
void gemm_v6(const float* __restrict__ A, const float* __restrict__ WT,
             float* __restrict__ C, int N)
{
    constexpr int NT  = K / BK;
    constexpr int CPL = BN / 64;
    constexpr int KRD = 1024 / (BN * 4);
    constexpr int J   = BK / (KRD * 4);
    typedef float cvec __attribute__((ext_vector_type(CPL)));
    __shared__ float wlds[2 * BK * BN];

    const int tid  = threadIdx.x;
    const int lane = tid & 63;
    const int wid  = __builtin_amdgcn_readfirstlane(tid >> 6);
    const int m0 = blockIdx.x * 32;
    const int n0 = blockIdx.y * BN;

    const float* Ar[8];
#pragma unroll
    for (int r = 0; r < 8; r++)
        Ar[r] = A + (size_t)(m0 + wid * 8 + r) * K;

    auto stage = [&](int dbuf, int k0) {
#pragma unroll
        for (int j = 0; j < J; j++) {
            int kb   = (wid * J + j) * KRD;
            int krow = kb + ((KRD == 2) ? (lane >> 5) : 0);
            int nofs = ((KRD == 2) ? (lane & 31) : lane) * 4;
            int dstw = __builtin_amdgcn_readfirstlane(dbuf * (BK * BN) + kb * BN);
            __builtin_amdgcn_global_load_lds(
                (const __attribute__((address_space(1))) void*)
                    (WT + (size_t)(k0 + krow) * N + n0 + nofs),
                (__attribute__((address_space(3))) void*)(wlds + dstw), 16, 0, 0);
        }
    };

    float acc[8][CPL];
#pragma unroll
    for (int r = 0; r < 8; r++)
#pragma unroll
        for (int g = 0; g < CPL; g++) acc[r][g] = 0.0f;

    stage(0, 0);
    __syncthreads();

    for (int t = 0; t < NT; t++) {
        const int k0 = t * BK;
        if (t + 1 < NT) stage((t + 1) & 1, k0 + BK);
        const float* Wb = wlds + (t & 1) * (BK * BN);
#pragma unroll
        for (int q = 0; q < BK / 4; q++) {
            f4 a4[8];
#pragma unroll
            for (int r = 0; r < 8; r++)
                a4[r] = *(const f4*)(Ar[r] + k0 + 4 * q);
#pragma unroll
            for (int e = 0; e < 4; e++) {
                cvec wv = *(const cvec*)(Wb + (4 * q + e) * BN + CPL * lane);
#pragma unroll
                for (int r = 0; r < 8; r++)
#pragma unroll
                    for (int g = 0; g < CPL; g++)
                        acc[r][g] = fmaf(a4[r][e], wv[g], acc[r][g]);
            }
        }
        __syncthreads();
    }

#pragma unroll
    for (int r = 0; r < 8; r++) {
        int m = m0 + wid * 8 + r;
        int orow = m;
        if (MODE == 2) {                         // (b*32+v)*96+s -> (b*96+s)*32+v
            int b = m / 3072, rr = m % 3072;
            int v = rr / 96, s = rr % 96;
            orow = (b * 96 + s) * 32 + v;
        } else if (MODE == 3) {                  // (b*96+s)*32+v -> (b*32+v)*96+s
            int b = m / 3072, rr = m % 3072;
            int s = rr / 32, v = rr % 32;
            orow = (b * 32 + v) * 96 + s;
        }
        cvec v;
#pragma unroll
        for (int g = 0; g < CPL; g++) v[g] = acc[r][g];
        *(cvec*)(C + (size_t)orow * N + n0 + CPL * lane) = v;
    }
}

// ---------------------------------------------------------------------------
// Fused conv + x_proj + dt_proj, BM=16 (grid 768 = 3 blocks/CU; As stride 17
// conflict-free).  Staging roles SPLIT: tid<128 computes conv-As (4 xz rows,
// 4 taps, SiLU); tid>=128 stages Ws -- the two streams run concurrently,
// shortening the pre-barrier critical path (r20 had all-256 on Ws after the
// conv threads finished).  16 | L so a tile never crosses a sequence.
// ---------------------------------------------------------------------------
__global__ __launch_bounds__(256)
void xproj_dt_conv(const float* __restrict__ xz,   // [M][1024]
                   const float* __restrict__ cw,   // [512][4]
                   const float* __restrict__ cb,   // [512]
                   const float* __restrict__ xpw,  // [48][512]
                   const float* __restrict__ dtw,  // [512][16]
                   const float* __restrict__ dtb,  // [512]
                   float* __restrict__ dbl,        // [M][48]
                   float* __restrict__ dty,        // [M][512]
                   int M, int L)
{
    constexpr int BM = 16, BN = 64, BK = 32, TN = 4;
    __shared__ float As[BK][BM + 1];             // stride 17: conflict-free
    __shared__ float Ws[BK][BN + 4];
    __shared__ float dbl_s[BM][52];

    const int tid = threadIdx.x;
    const int tx  = tid % (BN / TN);             // 0..15 (col group)
    const int ty  = tid / (BN / TN);             // 0..15 (row)
    const int m0  = blockIdx.x * BM;
    const int lmb = m0 % L;

    // conv staging role (tid < 128): row = tid>>3, kc = (tid&7)*4
    const int s_row = tid >> 3;
    const int s_kc  = (tid & 7) << 2;
    const int s_m   = m0 + s_row;
    const int s_lm  = lmb + s_row;

    float acc[TN];
#pragma unroll
    for (int j = 0; j < TN; j++) acc[j] = 0.0f;

    constexpr int F4R = BK / 4;                  // 8 f4 per Ws row

    for (int k0 = 0; k0 < 512; k0 += BK) {
        if (tid < 128) {
            // --- conv staging of As: 4 xz rows, 4 taps, SiLU ---
            const int col0 = k0 + s_kc;
            f4 xv[4];
#pragma unroll
            for (int j = 0; j < 4; j++) {
                if (s_lm - 3 + j >= 0)
                    xv[j] = *(const f4*)(xz + (size_t)(s_m - 3 + j) * 1024 + col0);
                else
                    xv[j] = (f4)0.0f;
            }
            f4 bv = *(const f4*)(cb + col0);
#pragma unroll
            for (int c = 0; c < 4; c++) {
                f4 w = *(const f4*)(cw + (size_t)(col0 + c) * 4);
                float v = bv[c];
#pragma unroll
                for (int j = 0; j < 4; j++)
                    v = fmaf(xv[j][c], w[j], v);
                As[s_kc + c][s_row] = silu_f(v);
            }
        } else {
            // --- Ws staging (xpw), 128 threads x 4 f4 ---
            const int t2 = tid - 128;
#pragma unroll
            for (int c = 0; c < 4; c++) {
                int idx = t2 + c * 128;          // 0..511
                int row = idx / F4R;
                int kc  = (idx % F4R) * 4;
                float4 v;
                if (row < 48) v = *(const float4*)(xpw + (size_t)row * 512 + k0 + kc);
                else          v = make_float4(0.f, 0.f, 0.f, 0.f);
                Ws[kc + 0][row] = v.x;
                Ws[kc + 1][row] = v.y;
                Ws[kc + 2][row] = v.z;
                Ws[kc + 3][row] = v.w;
            }
        }
        __syncthreads();

#pragma unroll
        for (int kk = 0; kk < BK; kk++) {
            float a = As[kk][ty];
            float w[TN];
#pragma unroll
            for (int j = 0; j < TN; j++) w[j] = Ws[kk][tx * TN + j];
#pragma unroll
            for (int j = 0; j < TN; j++)
                acc[j] = fmaf(a, w[j], acc[j]);
        }
        __syncthreads();
    }

    // store dbl tile: global (scan reads B,C) + LDS (dt phase)
#pragma unroll
    for (int j = 0; j < TN; j++) {
        int n = tx * TN + j;
        if (n < 48) {
            dbl[(size_t)(m0 + ty) * 48 + n] = acc[j];
            dbl_s[ty][n] = acc[j];
        }
    }
    __syncthreads();

    // dt phase: cols n = tid and tid+256; K=16 from LDS (broadcast reads)
    f4 wA[4], wB[4];
#pragma unroll
    for (int c = 0; c < 4; c++) {
        wA[c] = *(const f4*)(dtw + (size_t)tid * 16 + 4 * c);
        wB[c] = *(const f4*)(dtw + (size_t)(tid + 256) * 16 + 4 * c);
    }
    const float bA = dtb[tid], bB = dtb[tid + 256];
#pragma unroll 4
    for (int r = 0; r < BM; r++) {
        f4 d[4];
#pragma unroll
        for (int c = 0; c < 4; c++) d[c] = *(const f4*)(&dbl_s[r][4 * c]);
        float vA = bA, vB = bB;
#pragma unroll
        for (int c = 0; c < 4; c++)
#pragma unroll
            for (int e = 0; e < 4; e++) {
                vA = fmaf(d[c][e], wA[c][e], vA);
                vB = fmaf(d[c][e], wB[c][e], vB);
            }
        vA = (vA > 20.0f) ? vA : log1pf(__expf(vA));
        vB = (vB > 20.0f) ? vB : log1pf(__expf(vB));
        dty[(size_t)(m0 + r) * 512 + tid]       = vA;
        dty[(size_t)(m0 + r) * 512 + tid + 256] = vB;
    }
}

// ---------------------------------------------------------------------------
// Selective scan + skip + gate, 2-way state split (8 states/thread),
// depth-4 named-slot prefetch, conv fused via 3-register rolling window.
// L % 4 == 0 (96, 32).
// ---------------------------------------------------------------------------
__global__ __launch_bounds__(256, 4)
void scan_gate8c(float* __restrict__ dty,
                 const float* __restrict__ xz,
                 const float* __restrict__ dbl,
                 const float* __restrict__ cw,
                 const float* __restrict__ cb,
                 const float* __restrict__ A_log,
                 const float* __restrict__ Dvec,
                 int L)
{
    int bn = blockIdx.x >> 2;
    int e  = ((blockIdx.x & 3) << 7) + (threadIdx.x >> 1);
    int sh = (threadIdx.x & 1) << 3;       // state half: 0 or 8

    float Ae[8], h[8];
#pragma unroll
    for (int s = 0; s < 8; s++) {
        Ae[s] = -__expf(A_log[e * D_STATE + sh + s]);
        h[s]  = 0.0f;
    }
    const float De  = Dvec[e];
    const f4 cwe    = *(const f4*)(cw + (size_t)e * 4);
    const float cbe = cb[e];
    float w0 = 0.f, w1 = 0.f, w2 = 0.f;    // conv window: xi(l-3..l-1)

    const int base = bn * L;
    const int last = base + L - 1;

#define LOADS(tk, dt_, xi_, Ba_, Bb_, Ca_, Cb_, z_)                      \
    dt_ = dty[(size_t)(tk) * 512 + e];                                   \
    xi_ = xz [(size_t)(tk) * 1024 + e];                                  \
    Ba_ = *(const f4*)(dbl + (size_t)(tk) * 48 + 16 + sh);               \
    Bb_ = *(const f4*)(dbl + (size_t)(tk) * 48 + 20 + sh);               \
    Ca_ = *(const f4*)(dbl + (size_t)(tk) * 48 + 32 + sh);               \
    Cb_ = *(const f4*)(dbl + (size_t)(tk) * 48 + 36 + sh);               \
    z_  = xz [(size_t)(tk) * 1024 + 512 + e];

#define COMPUTE(tk, dt_, xi_, Ba_, Bb_, Ca_, Cb_, z_)                    \
    {                                                                    \
        float u = cbe;                                                   \
        u = fmaf(w0, cwe[0], u);                                         \
        u = fmaf(w1, cwe[1], u);                                         \
        u = fmaf(w2, cwe[2], u);                                         \
        u = fmaf(xi_, cwe[3], u);                                        \
        u = silu_f(u);                                                   \
        w0 = w1; w1 = w2; w2 = xi_;                                      \
        float y = 0.0f;                                                  \
        float du = (dt_) * u;                                            \
        _Pragma("unroll")                                                \
        for (int s = 0; s < 4; s++) {                                    \
            float dA = __expf((dt_) * Ae[s]);                            \
            h[s] = fmaf(dA, h[s], du * (Ba_)[s]);                        \
            y    = fmaf(h[s], (Ca_)[s], y);                              \
        }                                                                \
        _Pragma("unroll")                                                \
        for (int s = 0; s < 4; s++) {                                    \
            float dA = __expf((dt_) * Ae[4 + s]);                        \
            h[4 + s] = fmaf(dA, h[4 + s], du * (Bb_)[s]);                \
            y        = fmaf(h[4 + s], (Cb_)[s], y);                      \
        }                                                                \
        y += __shfl_xor(y, 1);                                           \
        if (sh == 0)                                                     \
            dty[(size_t)(tk) * 512 + e] = (y + u * De) * silu_f(z_);     \
    }

#define REFILL(slot_tk, dt_, xi_, Ba_, Bb_, Ca_, Cb_, z_)                \
    {                                                                    \
        int tp = (slot_tk) > last ? last : (slot_tk);                    \
        LOADS(tp, dt_, xi_, Ba_, Bb_, Ca_, Cb_, z_);                     \
    }

    float dt0, x0, z0, dt1, x1, z1, dt2, x2, z2, dt3, x3, z3;
    f4 Ba0, Bb0, Ca0, Cb0, Ba1, Bb1, Ca1, Cb1;
    f4 Ba2, Bb2, Ca2, Cb2, Ba3, Bb3, Ca3, Cb3;
    LOADS(base,     dt0, x0, Ba0, Bb0, Ca0, Cb0, z0);
    LOADS(base + 1, dt1, x1, Ba1, Bb1, Ca1, Cb1, z1);
    LOADS(base + 2, dt2, x2, Ba2, Bb2, Ca2, Cb2, z2);
    LOADS(base + 3, dt3, x3, Ba3, Bb3, Ca3, Cb3, z3);

    for (int l = 0; l < L; l += 4) {
        int tk = base + l;
        COMPUTE(tk,     dt0, x0, Ba0, Bb0, Ca0, Cb0, z0);
        REFILL(tk + 4,  dt0, x0, Ba0, Bb0, Ca0, Cb0, z0);
        COMPUTE(tk + 1, dt1, x1, Ba1, Bb1, Ca1, Cb1, z1);
        REFILL(tk + 5,  dt1, x1, Ba1, Bb1, Ca1, Cb1, z1);
        COMPUTE(tk + 2, dt2, x2, Ba2, Bb2, Ca2, Cb2, z2);
        REFILL(tk + 6,  dt2, x2, Ba2, Bb2, Ca2, Cb2, z2);
        COMPUTE(tk + 3, dt3, x3, Ba3, Bb3, Ca3, Cb3, z3);
        REFILL(tk + 7,  dt3, x3, Ba3, Bb3, Ca3, Cb3, z3);
    }
#undef LOADS
#undef COMPUTE
#undef REFILL
}

// ---------------------------------------------------------------------------
// One mamba stage (weights pre-transposed; conv fused; no xc buffer).
// ---------------------------------------------------------------------------
template<int OUTMODE>
static void run_stage(const float* xin,
                      const float* in_wT, const float* conv_w, const float* conv_b,
                      const float* xproj_w, const float* dt_w, const float* dt_b,
                      const float* A_log, const float* Dvec, const float* out_wT,
                      float* xz, float* dbl, float* dty, float* outp,
                      int Bn, int L, hipStream_t stream)
{
    const int M = TOKENS;
    // in_proj: [M,1024] = x[M,256] * in_w^T   (BN=256, BK=8, grid 384x4)
    gemm_v6<256, 256, 8, 0><<<dim3(M / 32, 1024 / 256), 256, 0, stream>>>(xin, in_wT, xz, 1024);
    // fused conv + x_proj + dt_proj (768 blocks, split staging)
    xproj_dt_conv<<<dim3(M / 16), 256, 0, stream>>>(
        xz, conv_w, conv_b, xproj_w, dt_w, dt_b, dbl, dty, M, L);
    // scan + skip + gate with fused conv (state-split 2x, depth-4 prefetch)
    scan_gate8c<<<dim3(Bn * 4), 256, 0, stream>>>(dty, xz, dbl, conv_w, conv_b,
                                                  A_log, Dvec, L);
    // out_proj with fused layout transpose (BN=128, BK=8, grid 384x2)
    gemm_v6<512, 128, 8, OUTMODE><<<dim3(M / 32, 256 / 128), 256, 0, stream>>>(dty, out_wT, outp, 256);
}

extern "C" void kernel_launch(void* const* d_in, const int* in_sizes, int n_in,
                              void* d_out, int out_size, void* d_ws, size_t ws_size,
                              hipStream_t stream)
{
    const float* x = (const float*)d_in[0];
    const float* t_in_w    = (const float*)d_in[1];
    const float* t_conv_w  = (const float*)d_in[2];
    const float* t_conv_b  = (const float*)d_in[3];
    const float* t_xproj_w = (const float*)d_in[4];
    const float* t_dt_w    = (const float*)d_in[5];
    const float* t_dt_b    = (const float*)d_in[6];
    const float* t_A_log   = (const float*)d_in[7];
    const float* t_D       = (const float*)d_in[8];
    const float* t_out_w   = (const float*)d_in[9];
    const float* d_in_w    = (const float*)d_in[10];
    const float* d_conv_w  = (const float*)d_in[11];
    const float* d_conv_b  = (const float*)d_in[12];
    const float* d_xproj_w = (const float*)d_in[13];
    const float* d_dt_w    = (const float*)d_in[14];
    const float* d_dt_b    = (const float*)d_in[15];
    const float* d_A_log   = (const float*)d_in[16];
    const float* d_D       = (const float*)d_in[17];
    const float* d_out_w   = (const float*)d_in[18];

    float* ws  = (float*)d_ws;
    float* xz  = ws;                                  // 12288*1024
    float* dbl = xz  + (size_t)TOKENS * 1024;         // 12288*48
    float* dty = dbl + (size_t)TOKENS * 48;           // 12288*512
    float* xt  = dty + (size_t)TOKENS * 512;          // 12288*256
    float* t_in_wT  = xt + (size_t)TOKENS * 256;      // [256][1024]
    float* t_out_wT = t_in_wT  + 262144;              // [512][256]
    float* d_in_wT  = t_out_wT + 131072;              // [256][1024]
    float* d_out_wT = d_in_wT  + 262144;              // [512][256]
    const size_t need_bytes =
        ((size_t)TOKENS * (1024 + 48 + 512 + 256) + 2 * (262144 + 131072)) * 4;
    if (ws_size < need_bytes) return;

    // pre-transpose the four big weights to k-major (batched: 2 dispatches)
    transpose_w2<<<dim3(256 / 32, 1024 / 32, 2), 256, 0, stream>>>(
        t_in_w, t_in_wT, d_in_w, d_in_wT, 1024, 256);
    transpose_w2<<<dim3(512 / 32, 256 / 32, 2), 256, 0, stream>>>(
        t_out_w, t_out_wT, d_out_w, d_out_wT, 256, 512);

    // stage 1: time scan, Bn = 128, L = 96
    run_stage<2>(x, t_in_wT, t_conv_w, t_conv_b, t_xproj_w, t_dt_w, t_dt_b,
                 t_A_log, t_D, t_out_wT, xz, dbl, dty, xt,
                 NB * NVAR, SEG, stream);
    // stage 2: dimension scan, Bn = 384, L = 32
    run_stage<3>(xt, d_in_wT, d_conv_w, d_conv_b, d_xproj_w, d_dt_w, d_dt_b,
                 d_A_log, d_D, d_out_wT, xz, dbl, dty, (float*)d_out,
                 NB * SEG, NVAR, stream);
}